// Round 7
// baseline (115.636 us; speedup 1.0000x reference)
//
#include <hip/hip_runtime.h>
#include <stdint.h>

#define M_DIM 4096
#define K_DIM 4096
#define N_DIM 4096

typedef int v4i __attribute__((ext_vector_type(4)));
typedef int int32x4 __attribute__((ext_vector_type(4)));

__device__ __forceinline__ void gload_lds16(const void* g, void* l) {
    __builtin_amdgcn_global_load_lds(
        (const __attribute__((address_space(1))) uint32_t*)g,
        (__attribute__((address_space(3))) uint32_t*)l, 16, 0, 0);
}

// ---------------- Pass 1: merged pack (A elementwise + B transpose) ----------------
__global__ void pack_ab_kernel(const int* __restrict__ a, char* __restrict__ a8,
                               const int* __restrict__ b, char* __restrict__ b8t) {
    __shared__ char tile[64][68];  // +4 pad (B branch only)
    if (blockIdx.x < 2048) {
        int idx = blockIdx.x * 256 + threadIdx.x;
        const int stride = 2048 * 256;
        const int total4 = M_DIM * K_DIM / 4;
        for (int i = idx; i < total4; i += stride) {
            int32x4 v = ((const int32x4*)a)[i];
            uint32_t p = (uint32_t)(v.x & 0xff) | ((uint32_t)(v.y & 0xff) << 8) |
                         ((uint32_t)(v.z & 0xff) << 16) | ((uint32_t)(v.w & 0xff) << 24);
            ((uint32_t*)a8)[i] = p;
        }
    } else {
        int bid2 = blockIdx.x - 2048;        // 0..4095
        int n0 = (bid2 & 63) * 64;
        int k0 = (bid2 >> 6) * 64;
        int tx = threadIdx.x & 63;
        int ty = threadIdx.x >> 6;  // 0..3
#pragma unroll
        for (int kk = 0; kk < 64; kk += 4) {
            tile[kk + ty][tx] = (char)b[(size_t)(k0 + kk + ty) * N_DIM + n0 + tx];
        }
        __syncthreads();
        int td = threadIdx.x & 15;  // dword index along k (0..15)
        int tn = threadIdx.x >> 4;  // 0..15
#pragma unroll
        for (int nn0 = 0; nn0 < 64; nn0 += 16) {
            int nn = nn0 + tn;
            uint32_t p = (uint32_t)(uint8_t)tile[td * 4 + 0][nn] |
                         ((uint32_t)(uint8_t)tile[td * 4 + 1][nn] << 8) |
                         ((uint32_t)(uint8_t)tile[td * 4 + 2][nn] << 16) |
                         ((uint32_t)(uint8_t)tile[td * 4 + 3][nn] << 24);
            *(uint32_t*)&b8t[(size_t)(n0 + nn) * K_DIM + k0 + td * 4] = p;
        }
    }
}

// ---------------- Pass 2: i8 GEMM, 256x256, A-in-LDS + B-direct-from-global (R7) ----------------
// BM=BN=256, window BK=64. 8 waves (2Mx4N), 512 threads.
// A: LDS 3-ring x 16 KiB (256 rows x 64B), involution swizzle (chunk c of row r at
//    slot c ^ ((r>>1)&3); pre-swizzled DMA source, swizzled read slot). Conflict-free.
// B: fragments loaded DIRECTLY global->register (16B contiguous per lane), register
//    double-buffer, prefetched 1 window ahead. No LDS, no swizzle needed.
//    -> LDS traffic/window: 128 KB -> 80 KB; B feed rides the idle VMEM pipe.
// Block->tile map bm=swz&15, bn=swz>>4: each XCD covers 2 bn x 16 bm -> B panel
//    (2 MB) L2-resident; A streams via latency-tolerant 2-window-lead DMA.
// Window w (entry queue [B(w):4, A(w+1):2]):
//   loadB(w+1)->regs(4)  stageA(w+2)->stg(2)   [queue=12]
//   vmcnt(6) -- drains exactly B(w)+A(w+1); leaves [B(w+1),A(w+2)]
//   BAR -- publishes A(w+1)
//   8 ds_read A-frags(w+1) -> alt regset ; 32 MFMA on current regset ; lgkmcnt(0)
// One barrier/window; vmcnt never 0 in loop; windows 62,63 peeled (vm4 -> vm0).
#define BM 256
#define BN 256
#define KTILES (K_DIM / 64)   // 64 windows of BK=64

#define BAR __builtin_amdgcn_s_barrier()
#define WAIT_VM6 asm volatile("s_waitcnt vmcnt(6)" ::: "memory")
#define WAIT_VM4 asm volatile("s_waitcnt vmcnt(4)" ::: "memory")
#define WAIT_VM2 asm volatile("s_waitcnt vmcnt(2)" ::: "memory")
#define WAIT_VM0 asm volatile("s_waitcnt vmcnt(0)" ::: "memory")
#define WAIT_LGKM0 asm volatile("s_waitcnt lgkmcnt(0)" ::: "memory")

#define RD_A(RA)                                                                        \
    _Pragma("unroll") for (int i_ = 0; i_ < 8; ++i_)                                    \
        RA[i_] = *(const v4i*)(lds + nxt + aOff + i_ * 1024);

#define SGB_HINT                                                                        \
    _Pragma("unroll") for (int g_ = 0; g_ < 8; ++g_) {                                  \
        __builtin_amdgcn_sched_group_barrier(0x100, 1, 0); /* 1 DS_READ */              \
        __builtin_amdgcn_sched_group_barrier(0x008, 3, 0); /* 3 MFMA */                 \
    }                                                                                   \
    __builtin_amdgcn_sched_group_barrier(0x008, 8, 0);

#define MFMA32(AF, BF)                                                                  \
    __builtin_amdgcn_s_setprio(1);                                                      \
    _Pragma("unroll") for (int i_ = 0; i_ < 8; ++i_)                                    \
    _Pragma("unroll") for (int j_ = 0; j_ < 4; ++j_)                                    \
        acc[i_][j_] = __builtin_amdgcn_mfma_i32_16x16x64_i8(AF[i_], BF[j_],             \
                                                            acc[i_][j_], 0, 0, 0);     \
    __builtin_amdgcn_s_setprio(0);

#define WINDOW(w, LA, LB, UA, UB)                                                       \
    {                                                                                   \
        loadB((w) + 1, LB);                                                             \
        stage((w) + 2, stg);                                                            \
        WAIT_VM6;                                                                       \
        BAR;                                                                            \
        RD_A(LA);                                                                       \
        SGB_HINT;                                                                       \
        MFMA32(UA, UB);                                                                 \
        WAIT_LGKM0;                                                                     \
        int t_ = cur; cur = nxt; nxt = stg; stg = t_;                                   \
    }

__global__ __launch_bounds__(512, 2) void gemm_i8_bd(const char* __restrict__ A8,
                                                     const char* __restrict__ B8T,
                                                     const float* __restrict__ scale,
                                                     float* __restrict__ out) {
    __shared__ char lds[49152];  // 3 x 16 KiB A-ring

    int tid = threadIdx.x;
    int wave = tid >> 6;
    int lane = tid & 63;
    int wr = wave >> 2;  // 0..1 -> 128 M-rows
    int wc = wave & 3;   // 0..3 -> 64 N-cols
    int l15 = lane & 15;

    // XCD-bijective swizzle; bn-major per XCD -> B panel L2-resident (2 bn / XCD)
    int bid = blockIdx.x;
    int swz = (bid & 7) * 32 + (bid >> 3);
    int bm = swz & 15;
    int bn = swz >> 4;  // 0..15

    // A staging: per-thread pre-swizzled global source; linear LDS dest
    int rA = tid >> 2;                                 // row 0..127 (+128 for 2nd gload)
    int cc = ((tid & 3) ^ ((tid >> 3) & 3)) << 4;      // pre-swizzled 16B chunk in 64B row
    const char* aSrc = A8 + (size_t)(bm * BM + rA) * K_DIM + cc;

    // B fragment source: row = bn*256 + wc*64 + j*16 + l15 ; chunk = (lane>>4)*16
    const char* bFragSrc =
        B8T + (size_t)(bn * BN + wc * 64 + l15) * K_DIM + ((lane >> 4) << 4);

    // A fragment read addressing (swizzled slot; 2-way max per 16-lane group = free)
    int slot = (((lane >> 4) ^ ((lane >> 1) & 3)) << 4);
    int aOff = wr * 8192 + l15 * 64 + slot;            // + buf + i*1024

    v4i acc[8][4];
#pragma unroll
    for (int i = 0; i < 8; ++i)
#pragma unroll
        for (int j = 0; j < 4; ++j) acc[i][j] = (v4i){0, 0, 0, 0};

    // stage one window of A (16 KB) into ring buffer bo: 2 gloads/thread
    auto stage = [&](int w, int bo) {
        const char* sa = aSrc + (size_t)w * 64;
        char* da = (char*)lds + bo + wave * 1024;
        gload_lds16(sa, da);
        gload_lds16(sa + (size_t)128 * K_DIM, da + 8192);
    };
    // load B fragments for window w into a register set: 4 global 16B loads
    auto loadB = [&](int w, v4i* dst) {
#pragma unroll
        for (int j = 0; j < 4; ++j)
            dst[j] = *(const v4i*)(bFragSrc + (size_t)j * 16 * K_DIM + (size_t)w * 64);
    };

    v4i pA[8], qA[8], pB[4], qB[4];

    // ---- prologue ----
    stage(0, 0);        // A(0)        [2]
    loadB(0, pB);       // B(0)        [6]
    stage(1, 16384);    // A(1)        [8]
    WAIT_VM2;           // drain A(0)+B(0); leaves A(1):2
    BAR;
#pragma unroll
    for (int i = 0; i < 8; ++i) pA[i] = *(const v4i*)(lds + 0 + aOff + i * 1024);

    int cur = 0, nxt = 16384, stg = 32768;

    // ---- main loop: windows 0..61 ----
    for (int kt = 0; kt < KTILES - 2; kt += 2) {
        WINDOW(kt, qA, qB, pA, pB);       // load B(kt+1)->qB, read A(kt+1)->qA, compute (pA,pB)
        WINDOW(kt + 1, pA, pB, qA, qB);   // load B(kt+2)->pB, read A(kt+2)->pA, compute (qA,qB)
    }

    // ---- peeled window 62 (entry queue [B(62):4, A(63):2]) ----
    loadB(63, qB);   // [10]
    WAIT_VM4;        // drains B(62)+A(63); leaves B(63):4
    BAR;
    RD_A(qA);
    MFMA32(pA, pB);
    // ---- peeled window 63 ----
    WAIT_VM0;        // B(63) landed
    MFMA32(qA, qB);  // compiler inserts lgkm wait for qA

    // ---- C write: out[row][col] = acc * scale[col] ----
    size_t orow0 = (size_t)bm * BM + wr * 128 + (lane >> 4) * 4;
    int ocol0 = bn * BN + wc * 64 + l15;
#pragma unroll
    for (int j = 0; j < 4; ++j) {
        int col = ocol0 + j * 16;
        float s = scale[col];
#pragma unroll
        for (int i = 0; i < 8; ++i) {
            size_t row = orow0 + (size_t)i * 16;
#pragma unroll
            for (int r = 0; r < 4; ++r) {
                out[(row + r) * N_DIM + col] = (float)acc[i][j][r] * s;
            }
        }
    }
}

// ---------------- Fallback: fused pack GEMM (no workspace needed) ----------------
#define FBM 128
#define FBN 128
#define FBK 64

__global__ __launch_bounds__(256) void gemm_i8_fused_kernel(const int* __restrict__ a,
                                                            const int* __restrict__ b,
                                                            const float* __restrict__ scale,
                                                            float* __restrict__ out) {
    __shared__ char As[FBM * FBK];
    __shared__ char Bs[FBN * FBK];

    int tid = threadIdx.x;
    int wave = tid >> 6;
    int lane = tid & 63;

    int nwg = gridDim.x;
    int cpx = nwg >> 3;
    int bid = blockIdx.x;
    int swz = (bid & 7) * cpx + (bid >> 3);
    int bm = swz >> 5;
    int bn = swz & 31;

    int f0 = tid * 16;
    int m0 = f0 >> 6;
    int k0 = f0 & 63;

    int nn = tid & 127;
    int kh = tid >> 7;  // 0..1

    int wr = wave >> 1;
    int wc = wave & 1;
    int lrow = lane & 15;
    int kgrp = (lane >> 4) * 16;

    v4i acc[4][4];
#pragma unroll
    for (int i = 0; i < 4; ++i)
#pragma unroll
        for (int j = 0; j < 4; ++j) acc[i][j] = (v4i){0, 0, 0, 0};

    const int kTiles = K_DIM / FBK;
    for (int kt = 0; kt < kTiles; ++kt) {
        __syncthreads();
#pragma unroll
        for (int r = 0; r < 2; ++r) {
            const int* src = a + (size_t)(bm * FBM + m0 + r * 64) * K_DIM + kt * FBK + k0;
            uint32_t pk[4];
#pragma unroll
            for (int q = 0; q < 4; ++q) {
                int32x4 v = *(const int32x4*)(src + q * 4);
                pk[q] = (uint32_t)(v.x & 0xff) | ((uint32_t)(v.y & 0xff) << 8) |
                        ((uint32_t)(v.z & 0xff) << 16) | ((uint32_t)(v.w & 0xff) << 24);
            }
            *(v4i*)&As[f0 + r * 4096] = (v4i){(int)pk[0], (int)pk[1], (int)pk[2], (int)pk[3]};
        }
#pragma unroll
        for (int d = 0; d < 8; ++d) {
            uint32_t p = 0;
#pragma unroll
            for (int i = 0; i < 4; ++i) {
                int kk = kt * FBK + kh * 32 + d * 4 + i;
                p |= (uint32_t)(b[(size_t)kk * N_DIM + bn * FBN + nn] & 0xff) << (8 * i);
            }
            *(uint32_t*)&Bs[nn * 64 + kh * 32 + d * 4] = p;
        }
        __syncthreads();

        v4i aF[4], bF[4];
#pragma unroll
        for (int i = 0; i < 4; ++i)
            aF[i] = *(const v4i*)&As[(wr * 64 + i * 16 + lrow) * FBK + kgrp];
#pragma unroll
        for (int j = 0; j < 4; ++j)
            bF[j] = *(const v4i*)&Bs[(wc * 64 + j * 16 + lrow) * FBK + kgrp];
#pragma unroll
        for (int i = 0; i < 4; ++i)
#pragma unroll
            for (int j = 0; j < 4; ++j)
                acc[i][j] = __builtin_amdgcn_mfma_i32_16x16x64_i8(aF[i], bF[j], acc[i][j], 0, 0, 0);
    }

    size_t orow0 = (size_t)bm * FBM + wr * 64;
    int ocol0 = bn * FBN + wc * 64;
#pragma unroll
    for (int j = 0; j < 4; ++j) {
        int col = ocol0 + j * 16 + lrow;
        float s = scale[col];
#pragma unroll
        for (int i = 0; i < 4; ++i) {
            size_t row = orow0 + i * 16 + (lane >> 4) * 4;
#pragma unroll
            for (int r = 0; r < 4; ++r) {
                out[(row + r) * N_DIM + col] = (float)acc[i][j][r] * s;
            }
        }
    }
}

extern "C" void kernel_launch(void* const* d_in, const int* in_sizes, int n_in,
                              void* d_out, int out_size, void* d_ws, size_t ws_size,
                              hipStream_t stream) {
    const int* a = (const int*)d_in[0];
    const int* b = (const int*)d_in[1];
    const float* scale = (const float*)d_in[2];
    float* out = (float*)d_out;

    size_t need = (size_t)M_DIM * K_DIM + (size_t)K_DIM * N_DIM;  // 32 MiB int8
    if (ws_size >= need) {
        char* a8 = (char*)d_ws;
        char* b8t = a8 + (size_t)M_DIM * K_DIM;
        pack_ab_kernel<<<2048 + 4096, 256, 0, stream>>>(a, a8, b, b8t);
        gemm_i8_bd<<<256, 512, 0, stream>>>(a8, b8t, scale, out);
    } else {
        gemm_i8_fused_kernel<<<1024, 256, 0, stream>>>(a, b, scale, out);
    }
}

// Round 8
// 97.050 us; speedup vs baseline: 1.1915x; 1.1915x over previous
//
#include <hip/hip_runtime.h>
#include <stdint.h>

#define M_DIM 4096
#define K_DIM 4096
#define N_DIM 4096

typedef int v4i __attribute__((ext_vector_type(4)));
typedef int int32x4 __attribute__((ext_vector_type(4)));

__device__ __forceinline__ void gload_lds16(const void* g, void* l) {
    __builtin_amdgcn_global_load_lds(
        (const __attribute__((address_space(1))) uint32_t*)g,
        (__attribute__((address_space(3))) uint32_t*)l, 16, 0, 0);
}

// ---------------- Pass 1: merged pack (A elementwise + B transpose) ----------------
__global__ void pack_ab_kernel(const int* __restrict__ a, char* __restrict__ a8,
                               const int* __restrict__ b, char* __restrict__ b8t) {
    __shared__ char tile[64][68];  // +4 pad (B branch only)
    if (blockIdx.x < 2048) {
        int idx = blockIdx.x * 256 + threadIdx.x;
        const int stride = 2048 * 256;
        const int total4 = M_DIM * K_DIM / 4;
        for (int i = idx; i < total4; i += stride) {
            int32x4 v = ((const int32x4*)a)[i];
            uint32_t p = (uint32_t)(v.x & 0xff) | ((uint32_t)(v.y & 0xff) << 8) |
                         ((uint32_t)(v.z & 0xff) << 16) | ((uint32_t)(v.w & 0xff) << 24);
            ((uint32_t*)a8)[i] = p;
        }
    } else {
        int bid2 = blockIdx.x - 2048;        // 0..4095
        int n0 = (bid2 & 63) * 64;
        int k0 = (bid2 >> 6) * 64;
        int tx = threadIdx.x & 63;
        int ty = threadIdx.x >> 6;  // 0..3
#pragma unroll
        for (int kk = 0; kk < 64; kk += 4) {
            tile[kk + ty][tx] = (char)b[(size_t)(k0 + kk + ty) * N_DIM + n0 + tx];
        }
        __syncthreads();
        int td = threadIdx.x & 15;  // dword index along k (0..15)
        int tn = threadIdx.x >> 4;  // 0..15
#pragma unroll
        for (int nn0 = 0; nn0 < 64; nn0 += 16) {
            int nn = nn0 + tn;
            uint32_t p = (uint32_t)(uint8_t)tile[td * 4 + 0][nn] |
                         ((uint32_t)(uint8_t)tile[td * 4 + 1][nn] << 8) |
                         ((uint32_t)(uint8_t)tile[td * 4 + 2][nn] << 16) |
                         ((uint32_t)(uint8_t)tile[td * 4 + 3][nn] << 24);
            *(uint32_t*)&b8t[(size_t)(n0 + nn) * K_DIM + k0 + td * 4] = p;
        }
    }
}

// ---------------- Pass 2: i8 GEMM, 256x256, BK=128 windows (R8: amortize fixed cost) ----
// BM=BN=256. 8 waves (2Mx4N), 512 threads. 32 windows of BK=128.
// LDS 128 KiB: 2 buffers x 64 KiB {A: 256 rows x 128B, B: same at +32KB}.
// Swizzle: chunk c (16B) of row r stored at slot c ^ (r&7)  (involution; applied
//   via pre-swizzled global source + linear DMA dest; reads XOR the slot).
//   Per 16-lane read group: 8 slots x 2 lanes -> same structure that measured 0 conflicts.
// Window w: { BAR_A (all waves done reading prior buffer);
//             stage S(w+1) -> other buf (8 gloads);
//             vmcnt(8)  -- entry outstanding S(w)=8, +8 issued -> drains S(w) exactly;
//             BAR_B (publishes S(w));
//             24 ds_read (fB0,fA0,fB1,fA1) ; SGB-interleaved 64 MFMA (kk0 then kk1) }
// 2 barriers + 1 counted wait per 128-K (was 1 BAR + 2 waits per 64-K) -> overhead/K halved.
// Tail window 31 peeled (vm0 once).
#define BM 256
#define BN 256
#define KTILES (K_DIM / 128)   // 32 windows

#define BAR __builtin_amdgcn_s_barrier()
#define WAIT_VM8 asm volatile("s_waitcnt vmcnt(8)" ::: "memory")
#define WAIT_VM0 asm volatile("s_waitcnt vmcnt(0)" ::: "memory")

// feasible interleave: 5 DS first (fB0[0..3]+fA0[0]) then 19x{1 DS,3 MFMA} + 7 MFMA
#define SGB_W128                                                                        \
    __builtin_amdgcn_sched_group_barrier(0x100, 5, 0);                                  \
    _Pragma("unroll") for (int g_ = 0; g_ < 19; ++g_) {                                 \
        __builtin_amdgcn_sched_group_barrier(0x100, 1, 0);                              \
        __builtin_amdgcn_sched_group_barrier(0x008, 3, 0);                              \
    }                                                                                   \
    __builtin_amdgcn_sched_group_barrier(0x008, 7, 0);

#define MFMA32(AF, BF)                                                                  \
    __builtin_amdgcn_s_setprio(1);                                                      \
    _Pragma("unroll") for (int i_ = 0; i_ < 8; ++i_)                                    \
    _Pragma("unroll") for (int j_ = 0; j_ < 4; ++j_)                                    \
        acc[i_][j_] = __builtin_amdgcn_mfma_i32_16x16x64_i8(AF[i_], BF[j_],             \
                                                            acc[i_][j_], 0, 0, 0);     \
    __builtin_amdgcn_s_setprio(0);

#define COMPUTE_WIN(cur)                                                                \
    {                                                                                   \
        _Pragma("unroll") for (int j_ = 0; j_ < 4; ++j_)                                \
            fB0[j_] = *(const v4i*)(lds + (cur) + bBase + j_ * 2048);                   \
        _Pragma("unroll") for (int i_ = 0; i_ < 8; ++i_)                                \
            fA0[i_] = *(const v4i*)(lds + (cur) + aBase + i_ * 2048);                   \
        _Pragma("unroll") for (int j_ = 0; j_ < 4; ++j_)                                \
            fB1[j_] = *(const v4i*)(lds + (cur) + ((bBase + j_ * 2048) ^ 64));          \
        _Pragma("unroll") for (int i_ = 0; i_ < 8; ++i_)                                \
            fA1[i_] = *(const v4i*)(lds + (cur) + ((aBase + i_ * 2048) ^ 64));          \
        SGB_W128;                                                                       \
        MFMA32(fA0, fB0);                                                               \
        MFMA32(fA1, fB1);                                                               \
    }

__global__ __launch_bounds__(512, 2) void gemm_i8_w128(const char* __restrict__ A8,
                                                       const char* __restrict__ B8T,
                                                       const float* __restrict__ scale,
                                                       float* __restrict__ out) {
    __shared__ char lds[131072];

    int tid = threadIdx.x;
    int wave = tid >> 6;
    int lane = tid & 63;
    int wr = wave >> 2;  // 0..1 -> 128 M-rows
    int wc = wave & 3;   // 0..3 -> 64 N-cols
    int l15 = lane & 15;
    int q = lane >> 4;   // 0..3

    // XCD-bijective swizzle (grid = 256, 256 % 8 == 0)
    int bid = blockIdx.x;
    int swz = (bid & 7) * 32 + (bid >> 3);
    int bm = swz >> 4;  // 0..15
    int bn = swz & 15;

    // staging: thread t covers row (t>>3)+64r, chunk (t&7); source pre-swizzled by row&7
    int sRow = tid >> 3;                               // 0..63
    int sCh = ((tid & 7) ^ (sRow & 7)) << 4;           // pre-swizzled 16B chunk in 128B row
    const char* aSrc = A8 + (size_t)(bm * BM + sRow) * K_DIM + sCh;
    const char* bSrc = B8T + (size_t)(bn * BN + sRow) * K_DIM + sCh;

    // fragment read addressing: slot = (kk*4 + q) ^ (row&7); row&7 == l15&7
    int slot0 = ((q ^ (l15 & 7)) << 4);                // kk0 slot; kk1 = ^64
    int aBase = (wr * 128 + l15) * 128 + slot0;        // + buf + i*2048 (rows i*16)
    int bBase = 32768 + (wc * 64 + l15) * 128 + slot0; // + buf + j*2048

    v4i acc[8][4];
#pragma unroll
    for (int i = 0; i < 8; ++i)
#pragma unroll
        for (int j = 0; j < 4; ++j) acc[i][j] = (v4i){0, 0, 0, 0};

    // stage one BK=128 window (A 32KB + B 32KB) into buffer bo: 8 gloads/thread
    auto stage = [&](int w, int bo) {
        const char* sa = aSrc + (size_t)w * 128;
        const char* sb = bSrc + (size_t)w * 128;
        char* da = (char*)lds + bo + wave * 1024;
#pragma unroll
        for (int r = 0; r < 4; ++r) {
            gload_lds16(sa + (size_t)r * 64 * K_DIM, da + r * 8192);
            gload_lds16(sb + (size_t)r * 64 * K_DIM, da + 32768 + r * 8192);
        }
    };

    v4i fA0[8], fB0[4], fA1[8], fB1[4];

    // ---- prologue: S(0) -> buf0 ----
    stage(0, 0);

    // ---- main loop: windows 0..30 ----
    for (int w = 0; w < KTILES - 1; ++w) {
        int cur = (w & 1) << 16;
        BAR;                       // all waves finished reading buf[cur^1] (window w-1)
        stage(w + 1, cur ^ 65536);
        WAIT_VM8;                  // drains S(w); S(w+1) stays in flight
        BAR;                       // publishes S(w)
        COMPUTE_WIN(cur);
    }

    // ---- tail: window 31 ----
    {
        int cur = ((KTILES - 1) & 1) << 16;
        WAIT_VM0;  // S(31) landed
        BAR;
        COMPUTE_WIN(cur);
    }

    // ---- C write: out[row][col] = acc * scale[col] ----
    size_t orow0 = (size_t)bm * BM + wr * 128 + (lane >> 4) * 4;
    int ocol0 = bn * BN + wc * 64 + l15;
#pragma unroll
    for (int j = 0; j < 4; ++j) {
        int col = ocol0 + j * 16;
        float s = scale[col];
#pragma unroll
        for (int i = 0; i < 8; ++i) {
            size_t row = orow0 + (size_t)i * 16;
#pragma unroll
            for (int r = 0; r < 4; ++r) {
                out[(row + r) * N_DIM + col] = (float)acc[i][j][r] * s;
            }
        }
    }
}

// ---------------- Fallback: fused pack GEMM (no workspace needed) ----------------
#define FBM 128
#define FBN 128
#define FBK 64

__global__ __launch_bounds__(256) void gemm_i8_fused_kernel(const int* __restrict__ a,
                                                            const int* __restrict__ b,
                                                            const float* __restrict__ scale,
                                                            float* __restrict__ out) {
    __shared__ char As[FBM * FBK];
    __shared__ char Bs[FBN * FBK];

    int tid = threadIdx.x;
    int wave = tid >> 6;
    int lane = tid & 63;

    int nwg = gridDim.x;
    int cpx = nwg >> 3;
    int bid = blockIdx.x;
    int swz = (bid & 7) * cpx + (bid >> 3);
    int bm = swz >> 5;
    int bn = swz & 31;

    int f0 = tid * 16;
    int m0 = f0 >> 6;
    int k0 = f0 & 63;

    int nn = tid & 127;
    int kh = tid >> 7;  // 0..1

    int wr = wave >> 1;
    int wc = wave & 1;
    int lrow = lane & 15;
    int kgrp = (lane >> 4) * 16;

    v4i acc[4][4];
#pragma unroll
    for (int i = 0; i < 4; ++i)
#pragma unroll
        for (int j = 0; j < 4; ++j) acc[i][j] = (v4i){0, 0, 0, 0};

    const int kTiles = K_DIM / FBK;
    for (int kt = 0; kt < kTiles; ++kt) {
        __syncthreads();
#pragma unroll
        for (int r = 0; r < 2; ++r) {
            const int* src = a + (size_t)(bm * FBM + m0 + r * 64) * K_DIM + kt * FBK + k0;
            uint32_t pk[4];
#pragma unroll
            for (int q = 0; q < 4; ++q) {
                int32x4 v = *(const int32x4*)(src + q * 4);
                pk[q] = (uint32_t)(v.x & 0xff) | ((uint32_t)(v.y & 0xff) << 8) |
                        ((uint32_t)(v.z & 0xff) << 16) | ((uint32_t)(v.w & 0xff) << 24);
            }
            *(v4i*)&As[f0 + r * 4096] = (v4i){(int)pk[0], (int)pk[1], (int)pk[2], (int)pk[3]};
        }
#pragma unroll
        for (int d = 0; d < 8; ++d) {
            uint32_t p = 0;
#pragma unroll
            for (int i = 0; i < 4; ++i) {
                int kk = kt * FBK + kh * 32 + d * 4 + i;
                p |= (uint32_t)(b[(size_t)kk * N_DIM + bn * FBN + nn] & 0xff) << (8 * i);
            }
            *(uint32_t*)&Bs[nn * 64 + kh * 32 + d * 4] = p;
        }
        __syncthreads();

        v4i aF[4], bF[4];
#pragma unroll
        for (int i = 0; i < 4; ++i)
            aF[i] = *(const v4i*)&As[(wr * 64 + i * 16 + lrow) * FBK + kgrp];
#pragma unroll
        for (int j = 0; j < 4; ++j)
            bF[j] = *(const v4i*)&Bs[(wc * 64 + j * 16 + lrow) * FBK + kgrp];
#pragma unroll
        for (int i = 0; i < 4; ++i)
#pragma unroll
            for (int j = 0; j < 4; ++j)
                acc[i][j] = __builtin_amdgcn_mfma_i32_16x16x64_i8(aF[i], bF[j], acc[i][j], 0, 0, 0);
    }

    size_t orow0 = (size_t)bm * FBM + wr * 64;
    int ocol0 = bn * FBN + wc * 64;
#pragma unroll
    for (int j = 0; j < 4; ++j) {
        int col = ocol0 + j * 16 + lrow;
        float s = scale[col];
#pragma unroll
        for (int i = 0; i < 4; ++i) {
            size_t row = orow0 + i * 16 + (lane >> 4) * 4;
#pragma unroll
            for (int r = 0; r < 4; ++r) {
                out[(row + r) * N_DIM + col] = (float)acc[i][j][r] * s;
            }
        }
    }
}

extern "C" void kernel_launch(void* const* d_in, const int* in_sizes, int n_in,
                              void* d_out, int out_size, void* d_ws, size_t ws_size,
                              hipStream_t stream) {
    const int* a = (const int*)d_in[0];
    const int* b = (const int*)d_in[1];
    const float* scale = (const float*)d_in[2];
    float* out = (float*)d_out;

    size_t need = (size_t)M_DIM * K_DIM + (size_t)K_DIM * N_DIM;  // 32 MiB int8
    if (ws_size >= need) {
        char* a8 = (char*)d_ws;
        char* b8t = a8 + (size_t)M_DIM * K_DIM;
        pack_ab_kernel<<<2048 + 4096, 256, 0, stream>>>(a, a8, b, b8t);
        gemm_i8_w128<<<256, 512, 0, stream>>>(a8, b8t, scale, out);
    } else {
        gemm_i8_fused_kernel<<<1024, 256, 0, stream>>>(a, b, scale, out);
    }
}